// Round 3
// baseline (1041.301 us; speedup 1.0000x reference)
//
#include <hip/hip_runtime.h>
#include <math.h>

// ---------------------------------------------------------------------------
// SpatialGNN: 3x GCN (residual) + 4-head GAT + MLP + log_softmax
// N=100000, E=1600000, IN=8, HID=64, HEADS=4, OUT=3
//
// R2 changes vs R1:
//  - 4-edge-parallel gathers: wave = 4 groups x 16 lanes, each group loads a
//    float4 (4 channels) of a different edge -> 4x fewer load issue slots,
//    4x more outstanding gathers; cross-group shfl_xor(16,32) reduce.
//  - Dropped softmax max-shift (shift-invariant, logits bounded) -> node_max
//    kernel and m4 buffer gone.
//  - Edge weights computed inline in gat_fused (gather a_src4[s] + exp once
//    per edge) -> edge_weight kernel + 51MB wts round-trip gone.
//  - att_coef fused into gcn_last epilogue.
//  - Features prescaled by dinv in producer epilogues (residual via rdinv)
//    -> no per-edge dinv load in GCN gathers.
// ---------------------------------------------------------------------------

__device__ __forceinline__ float leaky02(float v) { return v > 0.f ? v : 0.2f * v; }

// ---- CSR build ------------------------------------------------------------

__global__ void count_kernel(const int* __restrict__ dst, int E, int* __restrict__ counts) {
    int e = blockIdx.x * blockDim.x + threadIdx.x;
    if (e < E) atomicAdd(&counts[dst[e]], 1);
}

__global__ void scan_pass1(const int* __restrict__ counts, int n, int* __restrict__ blockSums) {
    __shared__ int sh[256];
    int base = blockIdx.x * 2048;
    int tid = threadIdx.x;
    int s = 0;
#pragma unroll
    for (int j = 0; j < 8; ++j) {
        int idx = base + tid * 8 + j;
        if (idx < n) s += counts[idx];
    }
    sh[tid] = s;
    __syncthreads();
    for (int off = 128; off > 0; off >>= 1) {
        if (tid < off) sh[tid] += sh[tid + off];
        __syncthreads();
    }
    if (tid == 0) blockSums[blockIdx.x] = sh[0];
}

__global__ void scan_pass2(const int* __restrict__ blockSums, int nb, int* __restrict__ blockOffs) {
    if (threadIdx.x == 0 && blockIdx.x == 0) {
        int run = 0;
        for (int i = 0; i < nb; ++i) { blockOffs[i] = run; run += blockSums[i]; }
    }
}

// also emits dinv, rdinv, and xs = dinv * x  (8-dim prescaled input features)
__global__ void scan_pass3(const int* __restrict__ counts, int n,
                           const int* __restrict__ blockOffs,
                           const float* __restrict__ x,
                           int* __restrict__ row_ptr, int* __restrict__ cursor,
                           float* __restrict__ dinv, float* __restrict__ rdinv,
                           float* __restrict__ xs) {
    __shared__ int sh[256];
    int base = blockIdx.x * 2048;
    int tid = threadIdx.x;
    int cnt[8];
    int local = 0;
#pragma unroll
    for (int j = 0; j < 8; ++j) {
        int idx = base + tid * 8 + j;
        cnt[j] = (idx < n) ? counts[idx] : 0;
        local += cnt[j];
    }
    sh[tid] = local;
    __syncthreads();
    for (int off = 1; off < 256; off <<= 1) {
        int v = (tid >= off) ? sh[tid - off] : 0;
        __syncthreads();
        sh[tid] += v;
        __syncthreads();
    }
    int run = blockOffs[blockIdx.x] + sh[tid] - local;
#pragma unroll
    for (int j = 0; j < 8; ++j) {
        int idx = base + tid * 8 + j;
        if (idx < n) {
            row_ptr[idx] = run;
            cursor[idx] = run;
            float dv = rsqrtf((float)(cnt[j] + 1));
            dinv[idx] = dv;
            rdinv[idx] = sqrtf((float)(cnt[j] + 1));
#pragma unroll
            for (int t = 0; t < 8; ++t) xs[idx * 8 + t] = dv * x[idx * 8 + t];
            run += cnt[j];
            if (idx == n - 1) row_ptr[n] = run;
        }
    }
}

__global__ void scatter_kernel(const int* __restrict__ src, const int* __restrict__ dst, int E,
                               int* __restrict__ cursor, int* __restrict__ col_src) {
    int e = blockIdx.x * blockDim.x + threadIdx.x;
    if (e < E) {
        int d = dst[e];
        int pos = atomicAdd(&cursor[d], 1);
        col_src[pos] = src[e];
    }
}

// ---- weight precomputes ---------------------------------------------------

__global__ void att_eff_kernel(const float* __restrict__ Wg,
                               const float* __restrict__ att_src, const float* __restrict__ att_dst,
                               float* __restrict__ wsrc_eff, float* __restrict__ wdst_eff) {
    int t = threadIdx.x;
    int k = t >> 2, h = t & 3;
    float ss = 0.f, sd = 0.f;
    for (int c = 0; c < 64; ++c) {
        float w = Wg[k * 256 + h * 64 + c];
        ss += w * att_src[h * 64 + c];
        sd += w * att_dst[h * 64 + c];
    }
    wsrc_eff[k * 4 + h] = ss;
    wdst_eff[k * 4 + h] = sd;
}

__global__ void ccomb_kernel(const float* __restrict__ Wg, const float* __restrict__ bg,
                             const float* __restrict__ wc1, const float* __restrict__ bc1,
                             float* __restrict__ Ccomb, float* __restrict__ bcomb) {
    int bid = blockIdx.x;   // 0..256
    int j = threadIdx.x;    // 64 threads
    if (bid < 256) {
        int h = bid >> 6, k = bid & 63;
        float s = 0.f;
        for (int c = 0; c < 64; ++c)
            s += Wg[k * 256 + h * 64 + c] * wc1[(h * 64 + c) * 64 + j];
        Ccomb[bid * 64 + j] = s;
    } else {
        float s = bc1[j];
        for (int i = 0; i < 256; ++i) s += bg[i] * wc1[i * 64 + j];
        bcomb[j] = s;
    }
}

// ---- GCN layer 1: 8-edge-parallel gather of xs (8-dim) --------------------

__global__ void gcn_layer1(const float* __restrict__ xs,
                           const float* __restrict__ W1, const float* __restrict__ b1,
                           const int* __restrict__ row_ptr, const int* __restrict__ col_src,
                           const float* __restrict__ dinv, int n,
                           float* __restrict__ hs1) {
    int tid = threadIdx.x, lane = tid & 63, wid = tid >> 6;
    int node = blockIdx.x * 4 + wid;
    if (node >= n) return;
    int g = lane >> 3, d = lane & 7;   // 8 edge slots x 8 dims
    int beg = row_ptr[node], end = row_ptr[node + 1];
    float acc = (g == 0) ? xs[node * 8 + d] : 0.f;   // self (prescaled)
    for (int e = beg; e < end; e += 16) {
        int e0 = e + g, e1 = e + 8 + g;
        int i0 = min(e0, end - 1), i1 = min(e1, end - 1);
        int s0 = col_src[i0], s1 = col_src[i1];
        float v0 = xs[s0 * 8 + d], v1 = xs[s1 * 8 + d];
        if (e0 < end) acc += v0;
        if (e1 < end) acc += v1;
    }
    acc += __shfl_xor(acc, 8);
    acc += __shfl_xor(acc, 16);
    acc += __shfl_xor(acc, 32);
    float di = dinv[node];
    acc *= di;
    float sum = b1[lane];
#pragma unroll
    for (int k = 0; k < 8; ++k) {
        float av = __shfl(acc, k);
        sum = fmaf(av, W1[k * 64 + lane], sum);
    }
    hs1[node * 64 + lane] = di * fmaxf(sum, 0.f);   // prescaled output
}

// ---- GCN layer 2/3: 4-edge-parallel gather (float4 channels) --------------
// hs_in is dinv-prescaled. out: if WRITE_SCALED: hs_out = dinv*(h_prev+relu(...))
// else raw h_out = h_prev+relu(...), plus fused attention coefficients.

template <bool LAST>
__global__ void gcn_layer64(const float* __restrict__ hs_in,
                            const float* __restrict__ W, const float* __restrict__ b,
                            const int* __restrict__ row_ptr, const int* __restrict__ col_src,
                            const float* __restrict__ dinv, const float* __restrict__ rdinv,
                            const float* __restrict__ wse, const float* __restrict__ wde,
                            int n,
                            float* __restrict__ hout,
                            float4* __restrict__ a_src4, float4* __restrict__ a_dst4) {
    __shared__ float Wl[64 * 64];
    int tid = threadIdx.x;
    for (int i = tid; i < 4096; i += 256) Wl[i] = W[i];
    __syncthreads();
    int lane = tid & 63, wid = tid >> 6;
    int node = blockIdx.x * 4 + wid;
    if (node >= n) return;
    int q = lane & 15, g = lane >> 4;   // 4 edge slots x 16 channel-quads
    const float4* hs4 = (const float4*)hs_in;
    int beg = row_ptr[node], end = row_ptr[node + 1];
    float4 self4 = hs4[node * 16 + q];
    float a0, a1, a2, a3;
    if (g == 0) { a0 = self4.x; a1 = self4.y; a2 = self4.z; a3 = self4.w; }
    else        { a0 = a1 = a2 = a3 = 0.f; }
    for (int e = beg; e < end; e += 8) {
        int e0 = e + g, e1 = e + 4 + g;
        int i0 = min(e0, end - 1), i1 = min(e1, end - 1);
        int s0 = col_src[i0], s1 = col_src[i1];
        float4 v0 = hs4[s0 * 16 + q];
        float4 v1 = hs4[s1 * 16 + q];
        if (e0 < end) { a0 += v0.x; a1 += v0.y; a2 += v0.z; a3 += v0.w; }
        if (e1 < end) { a0 += v1.x; a1 += v1.y; a2 += v1.z; a3 += v1.w; }
    }
    // reduce across the 4 edge groups
    float ac[4] = {a0, a1, a2, a3};
#pragma unroll
    for (int c = 0; c < 4; ++c) {
        ac[c] += __shfl_xor(ac[c], 16);
        ac[c] += __shfl_xor(ac[c], 32);
    }
    float di = dinv[node];
#pragma unroll
    for (int c = 0; c < 4; ++c) ac[c] *= di;
    // dense: sum[lane] = b[lane] + sum_k agg(k) * W[k][lane]
    float sum = b[lane];
#pragma unroll
    for (int k = 0; k < 64; ++k) {
        float av = __shfl(ac[k & 3], k >> 2);
        sum = fmaf(av, Wl[k * 64 + lane], sum);
    }
    float hprev = rdinv[node] * hs_in[node * 64 + lane];
    float hv = hprev + fmaxf(sum, 0.f);
    if (!LAST) {
        hout[node * 64 + lane] = di * hv;   // prescaled for next gather
    } else {
        hout[node * 64 + lane] = hv;        // raw h3 for GAT
        // fused attention coefficients: a_src/a_dst = h3 . w_eff per head
        const float4* wse4 = (const float4*)wse;
        const float4* wde4 = (const float4*)wde;
        float4 we = wse4[lane], wd = wde4[lane];
        float vs[4] = {hv * we.x, hv * we.y, hv * we.z, hv * we.w};
        float vd[4] = {hv * wd.x, hv * wd.y, hv * wd.z, hv * wd.w};
#pragma unroll
        for (int m = 32; m > 0; m >>= 1) {
#pragma unroll
            for (int h = 0; h < 4; ++h) {
                vs[h] += __shfl_xor(vs[h], m);
                vd[h] += __shfl_xor(vd[h], m);
            }
        }
        if (lane == 0) {
            a_src4[node] = make_float4(vs[0], vs[1], vs[2], vs[3]);
            a_dst4[node] = make_float4(vd[0], vd[1], vd[2], vd[3]);
        }
    }
}

// ---- GAT aggregate (inline exp weights) + folded MLP + log_softmax --------
// 2 nodes per wave; 4-edge-parallel gather; no max-shift (alpha is shift-inv).

__global__ void gat_fused(const float* __restrict__ h3,
                          const float4* __restrict__ a_src4, const float4* __restrict__ a_dst4,
                          const int* __restrict__ row_ptr, const int* __restrict__ col_src,
                          const float* __restrict__ Ccomb, const float* __restrict__ bcomb,
                          const float* __restrict__ wc2, const float* __restrict__ bc2,
                          int n, float* __restrict__ out) {
    int tid = threadIdx.x, lane = tid & 63, wid = tid >> 6;
    int node0 = (blockIdx.x * 4 + wid) * 2;
    if (node0 >= n) return;
    int nnodes = (node0 + 1 < n) ? 2 : 1;
    int q = lane & 15, g = lane >> 4;
    const float4* h34 = (const float4*)h3;

    float accq[2][4][4];   // [node][head][channel-in-quad]
#pragma unroll
    for (int h = 0; h < 4; ++h)
#pragma unroll
        for (int c = 0; c < 4; ++c) accq[1][h][c] = 0.f;

    for (int j = 0; j < nnodes; ++j) {
        int node = node0 + j;
        float4 ad = a_dst4[node];
        float4 asf = a_src4[node];
        float4 hself = h34[node * 16 + q];
        float A[4][4];
        float dh[4];
        {
            float w0 = __expf(leaky02(asf.x + ad.x));
            float w1 = __expf(leaky02(asf.y + ad.y));
            float w2 = __expf(leaky02(asf.z + ad.z));
            float w3 = __expf(leaky02(asf.w + ad.w));
            float m0 = (g == 0) ? 1.f : 0.f;
            dh[0] = m0 * w0; dh[1] = m0 * w1; dh[2] = m0 * w2; dh[3] = m0 * w3;
            A[0][0] = dh[0] * hself.x; A[0][1] = dh[0] * hself.y; A[0][2] = dh[0] * hself.z; A[0][3] = dh[0] * hself.w;
            A[1][0] = dh[1] * hself.x; A[1][1] = dh[1] * hself.y; A[1][2] = dh[1] * hself.z; A[1][3] = dh[1] * hself.w;
            A[2][0] = dh[2] * hself.x; A[2][1] = dh[2] * hself.y; A[2][2] = dh[2] * hself.z; A[2][3] = dh[2] * hself.w;
            A[3][0] = dh[3] * hself.x; A[3][1] = dh[3] * hself.y; A[3][2] = dh[3] * hself.z; A[3][3] = dh[3] * hself.w;
        }
        int beg = row_ptr[node], end = row_ptr[node + 1];
        for (int e = beg; e < end; e += 8) {
#pragma unroll
            for (int half = 0; half < 2; ++half) {
                int ei = e + half * 4 + g;
                int ii = min(ei, end - 1);
                int s = col_src[ii];
                float4 as = a_src4[s];
                float4 hv = h34[s * 16 + q];
                float valid = (ei < end) ? 1.f : 0.f;
                float w0 = valid * __expf(leaky02(as.x + ad.x));
                float w1 = valid * __expf(leaky02(as.y + ad.y));
                float w2 = valid * __expf(leaky02(as.z + ad.z));
                float w3 = valid * __expf(leaky02(as.w + ad.w));
                A[0][0] = fmaf(w0, hv.x, A[0][0]); A[0][1] = fmaf(w0, hv.y, A[0][1]);
                A[0][2] = fmaf(w0, hv.z, A[0][2]); A[0][3] = fmaf(w0, hv.w, A[0][3]);
                A[1][0] = fmaf(w1, hv.x, A[1][0]); A[1][1] = fmaf(w1, hv.y, A[1][1]);
                A[1][2] = fmaf(w1, hv.z, A[1][2]); A[1][3] = fmaf(w1, hv.w, A[1][3]);
                A[2][0] = fmaf(w2, hv.x, A[2][0]); A[2][1] = fmaf(w2, hv.y, A[2][1]);
                A[2][2] = fmaf(w2, hv.z, A[2][2]); A[2][3] = fmaf(w2, hv.w, A[2][3]);
                A[3][0] = fmaf(w3, hv.x, A[3][0]); A[3][1] = fmaf(w3, hv.y, A[3][1]);
                A[3][2] = fmaf(w3, hv.z, A[3][2]); A[3][3] = fmaf(w3, hv.w, A[3][3]);
                dh[0] += w0; dh[1] += w1; dh[2] += w2; dh[3] += w3;
            }
        }
        // reduce across 4 edge groups
#pragma unroll
        for (int h = 0; h < 4; ++h) {
#pragma unroll
            for (int c = 0; c < 4; ++c) {
                A[h][c] += __shfl_xor(A[h][c], 16);
                A[h][c] += __shfl_xor(A[h][c], 32);
            }
            dh[h] += __shfl_xor(dh[h], 16);
            dh[h] += __shfl_xor(dh[h], 32);
        }
#pragma unroll
        for (int h = 0; h < 4; ++h) {
            float r = 1.f / (dh[h] + 1e-16f);
#pragma unroll
            for (int c = 0; c < 4; ++c) accq[j][h][c] = A[h][c] * r;
        }
    }

    // z = relu(bcomb + sum_{h,k} acc_h(k) * Ccomb[h*64+k][lane])
    float z0 = bcomb[lane], z1 = z0;
#pragma unroll
    for (int k = 0; k < 64; ++k) {
#pragma unroll
        for (int h = 0; h < 4; ++h) {
            float c = Ccomb[(h * 64 + k) * 64 + lane];
            z0 = fmaf(__shfl(accq[0][h][k & 3], k >> 2), c, z0);
            z1 = fmaf(__shfl(accq[1][h][k & 3], k >> 2), c, z1);
        }
    }
    z0 = fmaxf(z0, 0.f);
    z1 = fmaxf(z1, 0.f);

    float w20 = wc2[lane * 3 + 0], w21 = wc2[lane * 3 + 1], w22 = wc2[lane * 3 + 2];
    float p0 = z0 * w20, p1 = z0 * w21, p2 = z0 * w22;
    float q0 = z1 * w20, q1 = z1 * w21, q2 = z1 * w22;
#pragma unroll
    for (int m = 32; m > 0; m >>= 1) {
        p0 += __shfl_xor(p0, m); p1 += __shfl_xor(p1, m); p2 += __shfl_xor(p2, m);
        q0 += __shfl_xor(q0, m); q1 += __shfl_xor(q1, m); q2 += __shfl_xor(q2, m);
    }
    if (lane == 0) {
        {
            float l0 = p0 + bc2[0], l1 = p1 + bc2[1], l2 = p2 + bc2[2];
            float mx = fmaxf(l0, fmaxf(l1, l2));
            float lse = mx + logf(expf(l0 - mx) + expf(l1 - mx) + expf(l2 - mx));
            out[node0 * 3 + 0] = l0 - lse;
            out[node0 * 3 + 1] = l1 - lse;
            out[node0 * 3 + 2] = l2 - lse;
        }
        if (nnodes == 2) {
            float l0 = q0 + bc2[0], l1 = q1 + bc2[1], l2 = q2 + bc2[2];
            float mx = fmaxf(l0, fmaxf(l1, l2));
            float lse = mx + logf(expf(l0 - mx) + expf(l1 - mx) + expf(l2 - mx));
            out[(node0 + 1) * 3 + 0] = l0 - lse;
            out[(node0 + 1) * 3 + 1] = l1 - lse;
            out[(node0 + 1) * 3 + 2] = l2 - lse;
        }
    }
}

// ---------------------------------------------------------------------------

extern "C" void kernel_launch(void* const* d_in, const int* in_sizes, int n_in,
                              void* d_out, int out_size, void* d_ws, size_t ws_size,
                              hipStream_t stream) {
    const float* x       = (const float*)d_in[0];
    const int*   ei      = (const int*)d_in[1];
    const float* w1      = (const float*)d_in[2];
    const float* b1      = (const float*)d_in[3];
    const float* w2      = (const float*)d_in[4];
    const float* b2      = (const float*)d_in[5];
    const float* w3      = (const float*)d_in[6];
    const float* b3      = (const float*)d_in[7];
    const float* wg      = (const float*)d_in[8];
    const float* bg      = (const float*)d_in[9];
    const float* att_s   = (const float*)d_in[10];
    const float* att_d   = (const float*)d_in[11];
    const float* wc1     = (const float*)d_in[12];
    const float* bc1     = (const float*)d_in[13];
    const float* wc2     = (const float*)d_in[14];
    const float* bc2     = (const float*)d_in[15];
    float* out = (float*)d_out;

    const int N = in_sizes[0] / 8;
    const int E = in_sizes[1] / 2;
    const int* srcv = ei;
    const int* dstv = ei + E;

    char* ws = (char*)d_ws;
    size_t off = 0;
    auto alloc = [&](size_t bytes) -> char* {
        char* p = ws + off;
        off += (bytes + 255) & ~(size_t)255;
        return p;
    };
    int*   counts    = (int*)alloc((size_t)N * 4);
    int*   row_ptr   = (int*)alloc((size_t)(N + 1) * 4);
    int*   cursor    = (int*)alloc((size_t)N * 4);
    int*   col_src   = (int*)alloc((size_t)E * 4);
    int*   blockSums = (int*)alloc(4096 * 4);
    int*   blockOffs = (int*)alloc(4096 * 4);
    float* dinv      = (float*)alloc((size_t)N * 4);
    float* rdinv     = (float*)alloc((size_t)N * 4);
    float* xs        = (float*)alloc((size_t)N * 8 * 4);
    float* a_src     = (float*)alloc((size_t)N * 16);
    float* a_dst     = (float*)alloc((size_t)N * 16);
    float* wse       = (float*)alloc(256 * 4);
    float* wde       = (float*)alloc(256 * 4);
    float* Ccomb     = (float*)alloc(256 * 64 * 4);
    float* bcomb     = (float*)alloc(64 * 4);
    float* bufA      = (float*)alloc((size_t)N * 64 * 4);   // hs1, later h3
    float* bufB      = (float*)alloc((size_t)N * 64 * 4);   // hs2
    float* hs1 = bufA;
    float* hs2 = bufB;
    float* h3  = bufA;   // hs1 dead after layer2's consumer (layer3 reads hs2 only)
    (void)ws_size; (void)n_in; (void)out_size;

    hipMemsetAsync(counts, 0, (size_t)N * 4, stream);

    const int TPB = 256;
    int gridE = (E + TPB - 1) / TPB;
    count_kernel<<<gridE, TPB, 0, stream>>>(dstv, E, counts);

    int NB = (N + 2047) / 2048;
    scan_pass1<<<NB, TPB, 0, stream>>>(counts, N, blockSums);
    scan_pass2<<<1, 64, 0, stream>>>(blockSums, NB, blockOffs);
    scan_pass3<<<NB, TPB, 0, stream>>>(counts, N, blockOffs, x,
                                       row_ptr, cursor, dinv, rdinv, xs);
    scatter_kernel<<<gridE, TPB, 0, stream>>>(srcv, dstv, E, cursor, col_src);

    att_eff_kernel<<<1, TPB, 0, stream>>>(wg, att_s, att_d, wse, wde);
    ccomb_kernel<<<257, 64, 0, stream>>>(wg, bg, wc1, bc1, Ccomb, bcomb);

    int gridN = (N + 3) / 4;
    gcn_layer1<<<gridN, TPB, 0, stream>>>(xs, w1, b1, row_ptr, col_src, dinv, N, hs1);
    gcn_layer64<false><<<gridN, TPB, 0, stream>>>(hs1, w2, b2, row_ptr, col_src,
                                                  dinv, rdinv, wse, wde, N, hs2,
                                                  nullptr, nullptr);
    gcn_layer64<true><<<gridN, TPB, 0, stream>>>(hs2, w3, b3, row_ptr, col_src,
                                                 dinv, rdinv, wse, wde, N, h3,
                                                 (float4*)a_src, (float4*)a_dst);

    int gridG = (N / 2 + 3) / 4;   // 2 nodes per wave, 4 waves per block
    gat_fused<<<gridG, TPB, 0, stream>>>(h3, (const float4*)a_src, (const float4*)a_dst,
                                         row_ptr, col_src, Ccomb, bcomb,
                                         wc2, bc2, N, out);
}

// Round 4
// 1005.742 us; speedup vs baseline: 1.0354x; 1.0354x over previous
//
#include <hip/hip_runtime.h>
#include <math.h>

// ---------------------------------------------------------------------------
// SpatialGNN: 3x GCN (residual) + 4-head GAT + MLP + log_softmax
// N=100000, E=1600000, IN=8, HID=64, HEADS=4, OUT=3
//
// R3 changes vs R2:
//  - FIX SCRATCH SPILL in gat_fused: R2's accq[2][4][4] was indexed by a
//    runtime loop var -> private-memory spill (WRITE_SIZE 614MB, occ 42%).
//    Now two explicit per-node gathers into separate compile-time-indexed
//    arrays (acc0/acc1) via a forceinline helper -> full SROA, VGPR-only.
//  - 16-edge-per-iteration gather unroll in gcn_layer64/gat_fused (4
//    independent dwordx4 gathers in flight per lane); 32/iter in gcn_layer1.
// ---------------------------------------------------------------------------

__device__ __forceinline__ float leaky02(float v) { return v > 0.f ? v : 0.2f * v; }

// ---- CSR build ------------------------------------------------------------

__global__ void count_kernel(const int* __restrict__ dst, int E, int* __restrict__ counts) {
    int e = blockIdx.x * blockDim.x + threadIdx.x;
    if (e < E) atomicAdd(&counts[dst[e]], 1);
}

__global__ void scan_pass1(const int* __restrict__ counts, int n, int* __restrict__ blockSums) {
    __shared__ int sh[256];
    int base = blockIdx.x * 2048;
    int tid = threadIdx.x;
    int s = 0;
#pragma unroll
    for (int j = 0; j < 8; ++j) {
        int idx = base + tid * 8 + j;
        if (idx < n) s += counts[idx];
    }
    sh[tid] = s;
    __syncthreads();
    for (int off = 128; off > 0; off >>= 1) {
        if (tid < off) sh[tid] += sh[tid + off];
        __syncthreads();
    }
    if (tid == 0) blockSums[blockIdx.x] = sh[0];
}

__global__ void scan_pass2(const int* __restrict__ blockSums, int nb, int* __restrict__ blockOffs) {
    if (threadIdx.x == 0 && blockIdx.x == 0) {
        int run = 0;
        for (int i = 0; i < nb; ++i) { blockOffs[i] = run; run += blockSums[i]; }
    }
}

// also emits dinv, rdinv, and xs = dinv * x  (8-dim prescaled input features)
__global__ void scan_pass3(const int* __restrict__ counts, int n,
                           const int* __restrict__ blockOffs,
                           const float* __restrict__ x,
                           int* __restrict__ row_ptr, int* __restrict__ cursor,
                           float* __restrict__ dinv, float* __restrict__ rdinv,
                           float* __restrict__ xs) {
    __shared__ int sh[256];
    int base = blockIdx.x * 2048;
    int tid = threadIdx.x;
    int cnt[8];
    int local = 0;
#pragma unroll
    for (int j = 0; j < 8; ++j) {
        int idx = base + tid * 8 + j;
        cnt[j] = (idx < n) ? counts[idx] : 0;
        local += cnt[j];
    }
    sh[tid] = local;
    __syncthreads();
    for (int off = 1; off < 256; off <<= 1) {
        int v = (tid >= off) ? sh[tid - off] : 0;
        __syncthreads();
        sh[tid] += v;
        __syncthreads();
    }
    int run = blockOffs[blockIdx.x] + sh[tid] - local;
#pragma unroll
    for (int j = 0; j < 8; ++j) {
        int idx = base + tid * 8 + j;
        if (idx < n) {
            row_ptr[idx] = run;
            cursor[idx] = run;
            float dv = rsqrtf((float)(cnt[j] + 1));
            dinv[idx] = dv;
            rdinv[idx] = sqrtf((float)(cnt[j] + 1));
#pragma unroll
            for (int t = 0; t < 8; ++t) xs[idx * 8 + t] = dv * x[idx * 8 + t];
            run += cnt[j];
            if (idx == n - 1) row_ptr[n] = run;
        }
    }
}

__global__ void scatter_kernel(const int* __restrict__ src, const int* __restrict__ dst, int E,
                               int* __restrict__ cursor, int* __restrict__ col_src) {
    int e = blockIdx.x * blockDim.x + threadIdx.x;
    if (e < E) {
        int d = dst[e];
        int pos = atomicAdd(&cursor[d], 1);
        col_src[pos] = src[e];
    }
}

// ---- weight precomputes ---------------------------------------------------

__global__ void att_eff_kernel(const float* __restrict__ Wg,
                               const float* __restrict__ att_src, const float* __restrict__ att_dst,
                               float* __restrict__ wsrc_eff, float* __restrict__ wdst_eff) {
    int t = threadIdx.x;
    int k = t >> 2, h = t & 3;
    float ss = 0.f, sd = 0.f;
    for (int c = 0; c < 64; ++c) {
        float w = Wg[k * 256 + h * 64 + c];
        ss += w * att_src[h * 64 + c];
        sd += w * att_dst[h * 64 + c];
    }
    wsrc_eff[k * 4 + h] = ss;
    wdst_eff[k * 4 + h] = sd;
}

__global__ void ccomb_kernel(const float* __restrict__ Wg, const float* __restrict__ bg,
                             const float* __restrict__ wc1, const float* __restrict__ bc1,
                             float* __restrict__ Ccomb, float* __restrict__ bcomb) {
    int bid = blockIdx.x;   // 0..256
    int j = threadIdx.x;    // 64 threads
    if (bid < 256) {
        int h = bid >> 6, k = bid & 63;
        float s = 0.f;
        for (int c = 0; c < 64; ++c)
            s += Wg[k * 256 + h * 64 + c] * wc1[(h * 64 + c) * 64 + j];
        Ccomb[bid * 64 + j] = s;
    } else {
        float s = bc1[j];
        for (int i = 0; i < 256; ++i) s += bg[i] * wc1[i * 64 + j];
        bcomb[j] = s;
    }
}

// ---- GCN layer 1: 8 groups x 8 dims, 32 edges per iteration ---------------

__global__ void gcn_layer1(const float* __restrict__ xs,
                           const float* __restrict__ W1, const float* __restrict__ b1,
                           const int* __restrict__ row_ptr, const int* __restrict__ col_src,
                           const float* __restrict__ dinv, int n,
                           float* __restrict__ hs1) {
    int tid = threadIdx.x, lane = tid & 63, wid = tid >> 6;
    int node = blockIdx.x * 4 + wid;
    if (node >= n) return;
    int g = lane >> 3, d = lane & 7;   // 8 edge slots x 8 dims
    int beg = row_ptr[node], end = row_ptr[node + 1];
    float acc = (g == 0) ? xs[node * 8 + d] : 0.f;   // self (prescaled)
    for (int e = beg; e < end; e += 32) {
#pragma unroll
        for (int u = 0; u < 4; ++u) {
            int ei = e + u * 8 + g;
            int ii = min(ei, end - 1);
            int s = col_src[ii];
            float v = xs[s * 8 + d];
            if (ei < end) acc += v;
        }
    }
    acc += __shfl_xor(acc, 8);
    acc += __shfl_xor(acc, 16);
    acc += __shfl_xor(acc, 32);
    float di = dinv[node];
    acc *= di;
    float sum = b1[lane];
#pragma unroll
    for (int k = 0; k < 8; ++k) {
        float av = __shfl(acc, k);
        sum = fmaf(av, W1[k * 64 + lane], sum);
    }
    hs1[node * 64 + lane] = di * fmaxf(sum, 0.f);   // prescaled output
}

// ---- GCN layer 2/3: 4 groups x 16 channel-quads, 16 edges per iteration ---

template <bool LAST>
__global__ void gcn_layer64(const float* __restrict__ hs_in,
                            const float* __restrict__ W, const float* __restrict__ b,
                            const int* __restrict__ row_ptr, const int* __restrict__ col_src,
                            const float* __restrict__ dinv, const float* __restrict__ rdinv,
                            const float* __restrict__ wse, const float* __restrict__ wde,
                            int n,
                            float* __restrict__ hout,
                            float4* __restrict__ a_src4, float4* __restrict__ a_dst4) {
    __shared__ float Wl[64 * 64];
    int tid = threadIdx.x;
    for (int i = tid; i < 4096; i += 256) Wl[i] = W[i];
    __syncthreads();
    int lane = tid & 63, wid = tid >> 6;
    int node = blockIdx.x * 4 + wid;
    if (node >= n) return;
    int q = lane & 15, g = lane >> 4;
    const float4* hs4 = (const float4*)hs_in;
    int beg = row_ptr[node], end = row_ptr[node + 1];
    float4 self4 = hs4[node * 16 + q];
    float ac[4];
    if (g == 0) { ac[0] = self4.x; ac[1] = self4.y; ac[2] = self4.z; ac[3] = self4.w; }
    else        { ac[0] = ac[1] = ac[2] = ac[3] = 0.f; }
    for (int e = beg; e < end; e += 16) {
#pragma unroll
        for (int u = 0; u < 4; ++u) {
            int ei = e + u * 4 + g;
            int ii = min(ei, end - 1);
            int s = col_src[ii];
            float4 v = hs4[s * 16 + q];
            if (ei < end) { ac[0] += v.x; ac[1] += v.y; ac[2] += v.z; ac[3] += v.w; }
        }
    }
#pragma unroll
    for (int c = 0; c < 4; ++c) {
        ac[c] += __shfl_xor(ac[c], 16);
        ac[c] += __shfl_xor(ac[c], 32);
    }
    float di = dinv[node];
#pragma unroll
    for (int c = 0; c < 4; ++c) ac[c] *= di;
    float sum = b[lane];
#pragma unroll
    for (int k = 0; k < 64; ++k) {
        float av = __shfl(ac[k & 3], k >> 2);
        sum = fmaf(av, Wl[k * 64 + lane], sum);
    }
    float hprev = rdinv[node] * hs_in[node * 64 + lane];
    float hv = hprev + fmaxf(sum, 0.f);
    if (!LAST) {
        hout[node * 64 + lane] = di * hv;   // prescaled for next gather
    } else {
        hout[node * 64 + lane] = hv;        // raw h3 for GAT
        const float4* wse4 = (const float4*)wse;
        const float4* wde4 = (const float4*)wde;
        float4 we = wse4[lane], wd = wde4[lane];
        float vs[4] = {hv * we.x, hv * we.y, hv * we.z, hv * we.w};
        float vd[4] = {hv * wd.x, hv * wd.y, hv * wd.z, hv * wd.w};
#pragma unroll
        for (int m = 32; m > 0; m >>= 1) {
#pragma unroll
            for (int h = 0; h < 4; ++h) {
                vs[h] += __shfl_xor(vs[h], m);
                vd[h] += __shfl_xor(vd[h], m);
            }
        }
        if (lane == 0) {
            a_src4[node] = make_float4(vs[0], vs[1], vs[2], vs[3]);
            a_dst4[node] = make_float4(vd[0], vd[1], vd[2], vd[3]);
        }
    }
}

// ---- GAT per-node gather (forceinline, compile-time-indexed accumulators) -

__device__ __forceinline__ void gat_gather_node(
    int node, int q, int g,
    const float4* __restrict__ h34,
    const float4* __restrict__ a_src4, const float4* __restrict__ a_dst4,
    const int* __restrict__ row_ptr, const int* __restrict__ col_src,
    float (&acc)[4][4]) {
    float4 ad = a_dst4[node];
    float4 asf = a_src4[node];
    float4 hself = h34[node * 16 + q];
    float A[4][4];
    float dh[4];
    {
        float w0 = __expf(leaky02(asf.x + ad.x));
        float w1 = __expf(leaky02(asf.y + ad.y));
        float w2 = __expf(leaky02(asf.z + ad.z));
        float w3 = __expf(leaky02(asf.w + ad.w));
        float m0 = (g == 0) ? 1.f : 0.f;
        dh[0] = m0 * w0; dh[1] = m0 * w1; dh[2] = m0 * w2; dh[3] = m0 * w3;
        A[0][0] = dh[0] * hself.x; A[0][1] = dh[0] * hself.y; A[0][2] = dh[0] * hself.z; A[0][3] = dh[0] * hself.w;
        A[1][0] = dh[1] * hself.x; A[1][1] = dh[1] * hself.y; A[1][2] = dh[1] * hself.z; A[1][3] = dh[1] * hself.w;
        A[2][0] = dh[2] * hself.x; A[2][1] = dh[2] * hself.y; A[2][2] = dh[2] * hself.z; A[2][3] = dh[2] * hself.w;
        A[3][0] = dh[3] * hself.x; A[3][1] = dh[3] * hself.y; A[3][2] = dh[3] * hself.z; A[3][3] = dh[3] * hself.w;
    }
    int beg = row_ptr[node], end = row_ptr[node + 1];
    for (int e = beg; e < end; e += 16) {
#pragma unroll
        for (int u = 0; u < 4; ++u) {
            int ei = e + u * 4 + g;
            int ii = min(ei, end - 1);
            int s = col_src[ii];
            float4 as = a_src4[s];
            float4 hv = h34[s * 16 + q];
            float valid = (ei < end) ? 1.f : 0.f;
            float w0 = valid * __expf(leaky02(as.x + ad.x));
            float w1 = valid * __expf(leaky02(as.y + ad.y));
            float w2 = valid * __expf(leaky02(as.z + ad.z));
            float w3 = valid * __expf(leaky02(as.w + ad.w));
            A[0][0] = fmaf(w0, hv.x, A[0][0]); A[0][1] = fmaf(w0, hv.y, A[0][1]);
            A[0][2] = fmaf(w0, hv.z, A[0][2]); A[0][3] = fmaf(w0, hv.w, A[0][3]);
            A[1][0] = fmaf(w1, hv.x, A[1][0]); A[1][1] = fmaf(w1, hv.y, A[1][1]);
            A[1][2] = fmaf(w1, hv.z, A[1][2]); A[1][3] = fmaf(w1, hv.w, A[1][3]);
            A[2][0] = fmaf(w2, hv.x, A[2][0]); A[2][1] = fmaf(w2, hv.y, A[2][1]);
            A[2][2] = fmaf(w2, hv.z, A[2][2]); A[2][3] = fmaf(w2, hv.w, A[2][3]);
            A[3][0] = fmaf(w3, hv.x, A[3][0]); A[3][1] = fmaf(w3, hv.y, A[3][1]);
            A[3][2] = fmaf(w3, hv.z, A[3][2]); A[3][3] = fmaf(w3, hv.w, A[3][3]);
            dh[0] += w0; dh[1] += w1; dh[2] += w2; dh[3] += w3;
        }
    }
#pragma unroll
    for (int h = 0; h < 4; ++h) {
#pragma unroll
        for (int c = 0; c < 4; ++c) {
            A[h][c] += __shfl_xor(A[h][c], 16);
            A[h][c] += __shfl_xor(A[h][c], 32);
        }
        dh[h] += __shfl_xor(dh[h], 16);
        dh[h] += __shfl_xor(dh[h], 32);
    }
#pragma unroll
    for (int h = 0; h < 4; ++h) {
        float r = 1.f / (dh[h] + 1e-16f);
#pragma unroll
        for (int c = 0; c < 4; ++c) acc[h][c] = A[h][c] * r;
    }
}

// ---- GAT aggregate + folded MLP + log_softmax (2 nodes per wave) ----------

__global__ void gat_fused(const float* __restrict__ h3,
                          const float4* __restrict__ a_src4, const float4* __restrict__ a_dst4,
                          const int* __restrict__ row_ptr, const int* __restrict__ col_src,
                          const float* __restrict__ Ccomb, const float* __restrict__ bcomb,
                          const float* __restrict__ wc2, const float* __restrict__ bc2,
                          int n, float* __restrict__ out) {
    int tid = threadIdx.x, lane = tid & 63, wid = tid >> 6;
    int node0 = (blockIdx.x * 4 + wid) * 2;
    if (node0 >= n) return;
    bool has2 = (node0 + 1 < n);
    int node1 = has2 ? node0 + 1 : node0;
    int q = lane & 15, g = lane >> 4;
    const float4* h34 = (const float4*)h3;

    float acc0[4][4], acc1[4][4];
    gat_gather_node(node0, q, g, h34, a_src4, a_dst4, row_ptr, col_src, acc0);
    gat_gather_node(node1, q, g, h34, a_src4, a_dst4, row_ptr, col_src, acc1);

    // z = relu(bcomb + sum_{h,k} acc_h(k) * Ccomb[h*64+k][lane])
    float z0 = bcomb[lane], z1 = z0;
#pragma unroll
    for (int k = 0; k < 64; ++k) {
#pragma unroll
        for (int h = 0; h < 4; ++h) {
            float c = Ccomb[(h * 64 + k) * 64 + lane];
            z0 = fmaf(__shfl(acc0[h][k & 3], k >> 2), c, z0);
            z1 = fmaf(__shfl(acc1[h][k & 3], k >> 2), c, z1);
        }
    }
    z0 = fmaxf(z0, 0.f);
    z1 = fmaxf(z1, 0.f);

    float w20 = wc2[lane * 3 + 0], w21 = wc2[lane * 3 + 1], w22 = wc2[lane * 3 + 2];
    float p0 = z0 * w20, p1 = z0 * w21, p2 = z0 * w22;
    float q0 = z1 * w20, q1 = z1 * w21, q2 = z1 * w22;
#pragma unroll
    for (int m = 32; m > 0; m >>= 1) {
        p0 += __shfl_xor(p0, m); p1 += __shfl_xor(p1, m); p2 += __shfl_xor(p2, m);
        q0 += __shfl_xor(q0, m); q1 += __shfl_xor(q1, m); q2 += __shfl_xor(q2, m);
    }
    if (lane == 0) {
        {
            float l0 = p0 + bc2[0], l1 = p1 + bc2[1], l2 = p2 + bc2[2];
            float mx = fmaxf(l0, fmaxf(l1, l2));
            float lse = mx + logf(expf(l0 - mx) + expf(l1 - mx) + expf(l2 - mx));
            out[node0 * 3 + 0] = l0 - lse;
            out[node0 * 3 + 1] = l1 - lse;
            out[node0 * 3 + 2] = l2 - lse;
        }
        if (has2) {
            float l0 = q0 + bc2[0], l1 = q1 + bc2[1], l2 = q2 + bc2[2];
            float mx = fmaxf(l0, fmaxf(l1, l2));
            float lse = mx + logf(expf(l0 - mx) + expf(l1 - mx) + expf(l2 - mx));
            out[(node0 + 1) * 3 + 0] = l0 - lse;
            out[(node0 + 1) * 3 + 1] = l1 - lse;
            out[(node0 + 1) * 3 + 2] = l2 - lse;
        }
    }
}

// ---------------------------------------------------------------------------

extern "C" void kernel_launch(void* const* d_in, const int* in_sizes, int n_in,
                              void* d_out, int out_size, void* d_ws, size_t ws_size,
                              hipStream_t stream) {
    const float* x       = (const float*)d_in[0];
    const int*   ei      = (const int*)d_in[1];
    const float* w1      = (const float*)d_in[2];
    const float* b1      = (const float*)d_in[3];
    const float* w2      = (const float*)d_in[4];
    const float* b2      = (const float*)d_in[5];
    const float* w3      = (const float*)d_in[6];
    const float* b3      = (const float*)d_in[7];
    const float* wg      = (const float*)d_in[8];
    const float* bg      = (const float*)d_in[9];
    const float* att_s   = (const float*)d_in[10];
    const float* att_d   = (const float*)d_in[11];
    const float* wc1     = (const float*)d_in[12];
    const float* bc1     = (const float*)d_in[13];
    const float* wc2     = (const float*)d_in[14];
    const float* bc2     = (const float*)d_in[15];
    float* out = (float*)d_out;

    const int N = in_sizes[0] / 8;
    const int E = in_sizes[1] / 2;
    const int* srcv = ei;
    const int* dstv = ei + E;

    char* ws = (char*)d_ws;
    size_t off = 0;
    auto alloc = [&](size_t bytes) -> char* {
        char* p = ws + off;
        off += (bytes + 255) & ~(size_t)255;
        return p;
    };
    int*   counts    = (int*)alloc((size_t)N * 4);
    int*   row_ptr   = (int*)alloc((size_t)(N + 1) * 4);
    int*   cursor    = (int*)alloc((size_t)N * 4);
    int*   col_src   = (int*)alloc((size_t)E * 4);
    int*   blockSums = (int*)alloc(4096 * 4);
    int*   blockOffs = (int*)alloc(4096 * 4);
    float* dinv      = (float*)alloc((size_t)N * 4);
    float* rdinv     = (float*)alloc((size_t)N * 4);
    float* xs        = (float*)alloc((size_t)N * 8 * 4);
    float* a_src     = (float*)alloc((size_t)N * 16);
    float* a_dst     = (float*)alloc((size_t)N * 16);
    float* wse       = (float*)alloc(256 * 4);
    float* wde       = (float*)alloc(256 * 4);
    float* Ccomb     = (float*)alloc(256 * 64 * 4);
    float* bcomb     = (float*)alloc(64 * 4);
    float* bufA      = (float*)alloc((size_t)N * 64 * 4);   // hs1, later h3
    float* bufB      = (float*)alloc((size_t)N * 64 * 4);   // hs2
    float* hs1 = bufA;
    float* hs2 = bufB;
    float* h3  = bufA;   // hs1 dead once layer3 runs (layer3 reads hs2 only)
    (void)ws_size; (void)n_in; (void)out_size;

    hipMemsetAsync(counts, 0, (size_t)N * 4, stream);

    const int TPB = 256;
    int gridE = (E + TPB - 1) / TPB;
    count_kernel<<<gridE, TPB, 0, stream>>>(dstv, E, counts);

    int NB = (N + 2047) / 2048;
    scan_pass1<<<NB, TPB, 0, stream>>>(counts, N, blockSums);
    scan_pass2<<<1, 64, 0, stream>>>(blockSums, NB, blockOffs);
    scan_pass3<<<NB, TPB, 0, stream>>>(counts, N, blockOffs, x,
                                       row_ptr, cursor, dinv, rdinv, xs);
    scatter_kernel<<<gridE, TPB, 0, stream>>>(srcv, dstv, E, cursor, col_src);

    att_eff_kernel<<<1, TPB, 0, stream>>>(wg, att_s, att_d, wse, wde);
    ccomb_kernel<<<257, 64, 0, stream>>>(wg, bg, wc1, bc1, Ccomb, bcomb);

    int gridN = (N + 3) / 4;
    gcn_layer1<<<gridN, TPB, 0, stream>>>(xs, w1, b1, row_ptr, col_src, dinv, N, hs1);
    gcn_layer64<false><<<gridN, TPB, 0, stream>>>(hs1, w2, b2, row_ptr, col_src,
                                                  dinv, rdinv, wse, wde, N, hs2,
                                                  nullptr, nullptr);
    gcn_layer64<true><<<gridN, TPB, 0, stream>>>(hs2, w3, b3, row_ptr, col_src,
                                                 dinv, rdinv, wse, wde, N, h3,
                                                 (float4*)a_src, (float4*)a_dst);

    int gridG = (N / 2 + 3) / 4;   // 2 nodes per wave, 4 waves per block
    gat_fused<<<gridG, TPB, 0, stream>>>(h3, (const float4*)a_src, (const float4*)a_dst,
                                         row_ptr, col_src, Ccomb, bcomb,
                                         wc2, bc2, N, out);
}

// Round 5
// 1003.256 us; speedup vs baseline: 1.0379x; 1.0025x over previous
//
#include <hip/hip_runtime.h>
#include <math.h>

// ---------------------------------------------------------------------------
// SpatialGNN: 3x GCN (residual) + 4-head GAT + MLP + log_softmax
// N=100000, E=1600000, IN=8, HID=64, HEADS=4, OUT=3
//
// R4 changes vs R3:
//  - Split gat_fused -> gat_agg (edge gather, writes normalized agg[n,256])
//    + mlp_kernel (Ccomb staged in LDS ONCE per block, streams 4 nodes/wave,
//    agg rows via wave-uniform scalar loads). Kills the per-wave 64KB Ccomb
//    reload (~1.6GB L1/L2 traffic). Striped x4 to reuse a 25.6MB agg slab.
//  - col_src preload trick in all gathers: one coalesced load covers 64
//    edges (cs = col_src[beg+base+lane]), indices distributed via __shfl ->
//    removes the per-edge dependent col_src->feature load chain.
// ---------------------------------------------------------------------------

__device__ __forceinline__ float leaky02(float v) { return v > 0.f ? v : 0.2f * v; }

// ---- CSR build ------------------------------------------------------------

__global__ void count_kernel(const int* __restrict__ dst, int E, int* __restrict__ counts) {
    int e = blockIdx.x * blockDim.x + threadIdx.x;
    if (e < E) atomicAdd(&counts[dst[e]], 1);
}

__global__ void scan_pass1(const int* __restrict__ counts, int n, int* __restrict__ blockSums) {
    __shared__ int sh[256];
    int base = blockIdx.x * 2048;
    int tid = threadIdx.x;
    int s = 0;
#pragma unroll
    for (int j = 0; j < 8; ++j) {
        int idx = base + tid * 8 + j;
        if (idx < n) s += counts[idx];
    }
    sh[tid] = s;
    __syncthreads();
    for (int off = 128; off > 0; off >>= 1) {
        if (tid < off) sh[tid] += sh[tid + off];
        __syncthreads();
    }
    if (tid == 0) blockSums[blockIdx.x] = sh[0];
}

__global__ void scan_pass2(const int* __restrict__ blockSums, int nb, int* __restrict__ blockOffs) {
    if (threadIdx.x == 0 && blockIdx.x == 0) {
        int run = 0;
        for (int i = 0; i < nb; ++i) { blockOffs[i] = run; run += blockSums[i]; }
    }
}

// also emits dinv, rdinv, and xs = dinv * x  (8-dim prescaled input features)
__global__ void scan_pass3(const int* __restrict__ counts, int n,
                           const int* __restrict__ blockOffs,
                           const float* __restrict__ x,
                           int* __restrict__ row_ptr, int* __restrict__ cursor,
                           float* __restrict__ dinv, float* __restrict__ rdinv,
                           float* __restrict__ xs) {
    __shared__ int sh[256];
    int base = blockIdx.x * 2048;
    int tid = threadIdx.x;
    int cnt[8];
    int local = 0;
#pragma unroll
    for (int j = 0; j < 8; ++j) {
        int idx = base + tid * 8 + j;
        cnt[j] = (idx < n) ? counts[idx] : 0;
        local += cnt[j];
    }
    sh[tid] = local;
    __syncthreads();
    for (int off = 1; off < 256; off <<= 1) {
        int v = (tid >= off) ? sh[tid - off] : 0;
        __syncthreads();
        sh[tid] += v;
        __syncthreads();
    }
    int run = blockOffs[blockIdx.x] + sh[tid] - local;
#pragma unroll
    for (int j = 0; j < 8; ++j) {
        int idx = base + tid * 8 + j;
        if (idx < n) {
            row_ptr[idx] = run;
            cursor[idx] = run;
            float dv = rsqrtf((float)(cnt[j] + 1));
            dinv[idx] = dv;
            rdinv[idx] = sqrtf((float)(cnt[j] + 1));
#pragma unroll
            for (int t = 0; t < 8; ++t) xs[idx * 8 + t] = dv * x[idx * 8 + t];
            run += cnt[j];
            if (idx == n - 1) row_ptr[n] = run;
        }
    }
}

__global__ void scatter_kernel(const int* __restrict__ src, const int* __restrict__ dst, int E,
                               int* __restrict__ cursor, int* __restrict__ col_src) {
    int e = blockIdx.x * blockDim.x + threadIdx.x;
    if (e < E) {
        int d = dst[e];
        int pos = atomicAdd(&cursor[d], 1);
        col_src[pos] = src[e];
    }
}

// ---- weight precomputes ---------------------------------------------------

__global__ void att_eff_kernel(const float* __restrict__ Wg,
                               const float* __restrict__ att_src, const float* __restrict__ att_dst,
                               float* __restrict__ wsrc_eff, float* __restrict__ wdst_eff) {
    int t = threadIdx.x;
    int k = t >> 2, h = t & 3;
    float ss = 0.f, sd = 0.f;
    for (int c = 0; c < 64; ++c) {
        float w = Wg[k * 256 + h * 64 + c];
        ss += w * att_src[h * 64 + c];
        sd += w * att_dst[h * 64 + c];
    }
    wsrc_eff[k * 4 + h] = ss;
    wdst_eff[k * 4 + h] = sd;
}

__global__ void ccomb_kernel(const float* __restrict__ Wg, const float* __restrict__ bg,
                             const float* __restrict__ wc1, const float* __restrict__ bc1,
                             float* __restrict__ Ccomb, float* __restrict__ bcomb) {
    int bid = blockIdx.x;   // 0..256
    int j = threadIdx.x;    // 64 threads
    if (bid < 256) {
        int h = bid >> 6, k = bid & 63;
        float s = 0.f;
        for (int c = 0; c < 64; ++c)
            s += Wg[k * 256 + h * 64 + c] * wc1[(h * 64 + c) * 64 + j];
        Ccomb[bid * 64 + j] = s;
    } else {
        float s = bc1[j];
        for (int i = 0; i < 256; ++i) s += bg[i] * wc1[i * 64 + j];
        bcomb[j] = s;
    }
}

// ---- GCN layer 1: 8 groups x 8 dims, col_src preload ----------------------

__global__ void gcn_layer1(const float* __restrict__ xs,
                           const float* __restrict__ W1, const float* __restrict__ b1,
                           const int* __restrict__ row_ptr, const int* __restrict__ col_src,
                           const float* __restrict__ dinv, int n,
                           float* __restrict__ hs1) {
    int tid = threadIdx.x, lane = tid & 63, wid = tid >> 6;
    int node = blockIdx.x * 4 + wid;
    if (node >= n) return;
    int g = lane >> 3, d = lane & 7;   // 8 edge slots x 8 dims
    int beg = row_ptr[node], end = row_ptr[node + 1];
    int deg = end - beg;
    float acc = (g == 0) ? xs[node * 8 + d] : 0.f;   // self (prescaled)
    for (int base = 0; base < deg; base += 64) {
        int cs = col_src[min(beg + base + lane, end - 1)];
        int lim = min(deg - base, 64);
        for (int chunk = 0; chunk < lim; chunk += 32) {
#pragma unroll
            for (int u = 0; u < 4; ++u) {
                int eo = chunk + u * 8 + g;
                int s = __shfl(cs, eo);
                float v = xs[s * 8 + d];
                if (eo < lim) acc += v;
            }
        }
    }
    acc += __shfl_xor(acc, 8);
    acc += __shfl_xor(acc, 16);
    acc += __shfl_xor(acc, 32);
    float di = dinv[node];
    acc *= di;
    float sum = b1[lane];
#pragma unroll
    for (int k = 0; k < 8; ++k) {
        float av = __shfl(acc, k);
        sum = fmaf(av, W1[k * 64 + lane], sum);
    }
    hs1[node * 64 + lane] = di * fmaxf(sum, 0.f);   // prescaled output
}

// ---- GCN layer 2/3: 4 groups x 16 channel-quads, col_src preload ----------

template <bool LAST>
__global__ void gcn_layer64(const float* __restrict__ hs_in,
                            const float* __restrict__ W, const float* __restrict__ b,
                            const int* __restrict__ row_ptr, const int* __restrict__ col_src,
                            const float* __restrict__ dinv, const float* __restrict__ rdinv,
                            const float* __restrict__ wse, const float* __restrict__ wde,
                            int n,
                            float* __restrict__ hout,
                            float4* __restrict__ a_src4, float4* __restrict__ a_dst4) {
    __shared__ float Wl[64 * 64];
    int tid = threadIdx.x;
    for (int i = tid; i < 4096; i += 256) Wl[i] = W[i];
    __syncthreads();
    int lane = tid & 63, wid = tid >> 6;
    int node = blockIdx.x * 4 + wid;
    if (node >= n) return;
    int q = lane & 15, g = lane >> 4;
    const float4* hs4 = (const float4*)hs_in;
    int beg = row_ptr[node], end = row_ptr[node + 1];
    int deg = end - beg;
    float4 self4 = hs4[node * 16 + q];
    float ac[4];
    if (g == 0) { ac[0] = self4.x; ac[1] = self4.y; ac[2] = self4.z; ac[3] = self4.w; }
    else        { ac[0] = ac[1] = ac[2] = ac[3] = 0.f; }
    for (int base = 0; base < deg; base += 64) {
        int cs = col_src[min(beg + base + lane, end - 1)];
        int lim = min(deg - base, 64);
        for (int chunk = 0; chunk < lim; chunk += 16) {
#pragma unroll
            for (int u = 0; u < 4; ++u) {
                int eo = chunk + u * 4 + g;
                int s = __shfl(cs, eo);
                float4 v = hs4[s * 16 + q];
                if (eo < lim) { ac[0] += v.x; ac[1] += v.y; ac[2] += v.z; ac[3] += v.w; }
            }
        }
    }
#pragma unroll
    for (int c = 0; c < 4; ++c) {
        ac[c] += __shfl_xor(ac[c], 16);
        ac[c] += __shfl_xor(ac[c], 32);
    }
    float di = dinv[node];
#pragma unroll
    for (int c = 0; c < 4; ++c) ac[c] *= di;
    float sum = b[lane];
#pragma unroll
    for (int k = 0; k < 64; ++k) {
        float av = __shfl(ac[k & 3], k >> 2);
        sum = fmaf(av, Wl[k * 64 + lane], sum);
    }
    float hprev = rdinv[node] * hs_in[node * 64 + lane];
    float hv = hprev + fmaxf(sum, 0.f);
    if (!LAST) {
        hout[node * 64 + lane] = di * hv;   // prescaled for next gather
    } else {
        hout[node * 64 + lane] = hv;        // raw h3 for GAT
        const float4* wse4 = (const float4*)wse;
        const float4* wde4 = (const float4*)wde;
        float4 we = wse4[lane], wd = wde4[lane];
        float vs[4] = {hv * we.x, hv * we.y, hv * we.z, hv * we.w};
        float vd[4] = {hv * wd.x, hv * wd.y, hv * wd.z, hv * wd.w};
#pragma unroll
        for (int m = 32; m > 0; m >>= 1) {
#pragma unroll
            for (int h = 0; h < 4; ++h) {
                vs[h] += __shfl_xor(vs[h], m);
                vd[h] += __shfl_xor(vd[h], m);
            }
        }
        if (lane == 0) {
            a_src4[node] = make_float4(vs[0], vs[1], vs[2], vs[3]);
            a_dst4[node] = make_float4(vd[0], vd[1], vd[2], vd[3]);
        }
    }
}

// ---- GAT aggregate: 1 node/wave, writes normalized agg[node-nbase][256] ---

__device__ __forceinline__ float sel4(int g, float v0, float v1, float v2, float v3) {
    return g == 0 ? v0 : g == 1 ? v1 : g == 2 ? v2 : v3;
}

__global__ void gat_agg(const float* __restrict__ h3,
                        const float4* __restrict__ a_src4, const float4* __restrict__ a_dst4,
                        const int* __restrict__ row_ptr, const int* __restrict__ col_src,
                        int nbase, int ncount, float* __restrict__ aggout) {
    int tid = threadIdx.x, lane = tid & 63, wid = tid >> 6;
    int li = blockIdx.x * 4 + wid;
    if (li >= ncount) return;
    int node = nbase + li;
    int q = lane & 15, g = lane >> 4;
    const float4* h34 = (const float4*)h3;

    float4 ad = a_dst4[node];
    float4 asf = a_src4[node];
    float4 hself = h34[node * 16 + q];
    float A[4][4], dh[4];
    {
        float w0 = __expf(leaky02(asf.x + ad.x));
        float w1 = __expf(leaky02(asf.y + ad.y));
        float w2 = __expf(leaky02(asf.z + ad.z));
        float w3 = __expf(leaky02(asf.w + ad.w));
        float m0 = (g == 0) ? 1.f : 0.f;
        dh[0] = m0 * w0; dh[1] = m0 * w1; dh[2] = m0 * w2; dh[3] = m0 * w3;
        A[0][0] = dh[0] * hself.x; A[0][1] = dh[0] * hself.y; A[0][2] = dh[0] * hself.z; A[0][3] = dh[0] * hself.w;
        A[1][0] = dh[1] * hself.x; A[1][1] = dh[1] * hself.y; A[1][2] = dh[1] * hself.z; A[1][3] = dh[1] * hself.w;
        A[2][0] = dh[2] * hself.x; A[2][1] = dh[2] * hself.y; A[2][2] = dh[2] * hself.z; A[2][3] = dh[2] * hself.w;
        A[3][0] = dh[3] * hself.x; A[3][1] = dh[3] * hself.y; A[3][2] = dh[3] * hself.z; A[3][3] = dh[3] * hself.w;
    }
    int beg = row_ptr[node], end = row_ptr[node + 1];
    int deg = end - beg;
    for (int base = 0; base < deg; base += 64) {
        int cs = col_src[min(beg + base + lane, end - 1)];
        int lim = min(deg - base, 64);
        for (int chunk = 0; chunk < lim; chunk += 16) {
#pragma unroll
            for (int u = 0; u < 4; ++u) {
                int eo = chunk + u * 4 + g;
                int s = __shfl(cs, eo);
                float4 as = a_src4[s];
                float4 hv = h34[s * 16 + q];
                float valid = (eo < lim) ? 1.f : 0.f;
                float w0 = valid * __expf(leaky02(as.x + ad.x));
                float w1 = valid * __expf(leaky02(as.y + ad.y));
                float w2 = valid * __expf(leaky02(as.z + ad.z));
                float w3 = valid * __expf(leaky02(as.w + ad.w));
                A[0][0] = fmaf(w0, hv.x, A[0][0]); A[0][1] = fmaf(w0, hv.y, A[0][1]);
                A[0][2] = fmaf(w0, hv.z, A[0][2]); A[0][3] = fmaf(w0, hv.w, A[0][3]);
                A[1][0] = fmaf(w1, hv.x, A[1][0]); A[1][1] = fmaf(w1, hv.y, A[1][1]);
                A[1][2] = fmaf(w1, hv.z, A[1][2]); A[1][3] = fmaf(w1, hv.w, A[1][3]);
                A[2][0] = fmaf(w2, hv.x, A[2][0]); A[2][1] = fmaf(w2, hv.y, A[2][1]);
                A[2][2] = fmaf(w2, hv.z, A[2][2]); A[2][3] = fmaf(w2, hv.w, A[2][3]);
                A[3][0] = fmaf(w3, hv.x, A[3][0]); A[3][1] = fmaf(w3, hv.y, A[3][1]);
                A[3][2] = fmaf(w3, hv.z, A[3][2]); A[3][3] = fmaf(w3, hv.w, A[3][3]);
                dh[0] += w0; dh[1] += w1; dh[2] += w2; dh[3] += w3;
            }
        }
    }
#pragma unroll
    for (int h = 0; h < 4; ++h) {
#pragma unroll
        for (int c = 0; c < 4; ++c) {
            A[h][c] += __shfl_xor(A[h][c], 16);
            A[h][c] += __shfl_xor(A[h][c], 32);
        }
        dh[h] += __shfl_xor(dh[h], 16);
        dh[h] += __shfl_xor(dh[h], 32);
    }
    float r0 = 1.f / (dh[0] + 1e-16f);
    float r1 = 1.f / (dh[1] + 1e-16f);
    float r2 = 1.f / (dh[2] + 1e-16f);
    float r3 = 1.f / (dh[3] + 1e-16f);
    // group g stores head g's quad: agg[li][g*64 + q*4 .. +3]
    float4 v;
    v.x = sel4(g, A[0][0] * r0, A[1][0] * r1, A[2][0] * r2, A[3][0] * r3);
    v.y = sel4(g, A[0][1] * r0, A[1][1] * r1, A[2][1] * r2, A[3][1] * r3);
    v.z = sel4(g, A[0][2] * r0, A[1][2] * r1, A[2][2] * r2, A[3][2] * r3);
    v.w = sel4(g, A[0][3] * r0, A[1][3] * r1, A[2][3] * r2, A[3][3] * r3);
    *(float4*)(aggout + (size_t)li * 256 + g * 64 + q * 4) = v;
}

// ---- MLP: Ccomb staged in LDS once/block, 4 nodes/wave, scalar agg loads --

__global__ __launch_bounds__(256) void mlp_kernel(
        const float* __restrict__ agg,
        const float* __restrict__ Ccomb, const float* __restrict__ bcomb,
        const float* __restrict__ wc2, const float* __restrict__ bc2,
        int nbase, int ncount, float* __restrict__ out) {
    __shared__ float Cl[256 * 64];
    int tid = threadIdx.x;
    {
        const float4* C4 = (const float4*)Ccomb;
        float4* Cl4 = (float4*)Cl;
        for (int i = tid; i < 4096; i += 256) Cl4[i] = C4[i];
    }
    __syncthreads();
    int lane = tid & 63;
    int wid = __builtin_amdgcn_readfirstlane(tid >> 6);
    int nwaves = gridDim.x * 4;
    int gw = blockIdx.x * 4 + wid;
    float bz = bcomb[lane];
    float w20 = wc2[lane * 3 + 0], w21 = wc2[lane * 3 + 1], w22 = wc2[lane * 3 + 2];
    float bb0 = bc2[0], bb1 = bc2[1], bb2 = bc2[2];
    int nquads = (ncount + 3) >> 2;
    int limax = ncount - 1;
    for (int qd = gw; qd < nquads; qd += nwaves) {
        int l0 = min(qd * 4 + 0, limax);
        int l1 = min(qd * 4 + 1, limax);
        int l2 = min(qd * 4 + 2, limax);
        int l3 = min(qd * 4 + 3, limax);
        const float* a0 = agg + (size_t)l0 * 256;
        const float* a1 = agg + (size_t)l1 * 256;
        const float* a2 = agg + (size_t)l2 * 256;
        const float* a3 = agg + (size_t)l3 * 256;
        float z0 = bz, z1 = bz, z2 = bz, z3 = bz;
#pragma unroll 16
        for (int i = 0; i < 256; ++i) {
            float c = Cl[i * 64 + lane];
            z0 = fmaf(a0[i], c, z0);
            z1 = fmaf(a1[i], c, z1);
            z2 = fmaf(a2[i], c, z2);
            z3 = fmaf(a3[i], c, z3);
        }
        z0 = fmaxf(z0, 0.f); z1 = fmaxf(z1, 0.f);
        z2 = fmaxf(z2, 0.f); z3 = fmaxf(z3, 0.f);
        float p[12];
        p[0] = z0 * w20; p[1] = z0 * w21; p[2] = z0 * w22;
        p[3] = z1 * w20; p[4] = z1 * w21; p[5] = z1 * w22;
        p[6] = z2 * w20; p[7] = z2 * w21; p[8] = z2 * w22;
        p[9] = z3 * w20; p[10] = z3 * w21; p[11] = z3 * w22;
#pragma unroll
        for (int m = 32; m > 0; m >>= 1) {
#pragma unroll
            for (int t = 0; t < 12; ++t) p[t] += __shfl_xor(p[t], m);
        }
        if (lane == 0) {
            int ls[4] = {l0, l1, l2, l3};
#pragma unroll
            for (int m = 0; m < 4; ++m) {
                float e0 = p[m * 3 + 0] + bb0, e1 = p[m * 3 + 1] + bb1, e2 = p[m * 3 + 2] + bb2;
                float mx = fmaxf(e0, fmaxf(e1, e2));
                float lse = mx + logf(expf(e0 - mx) + expf(e1 - mx) + expf(e2 - mx));
                int nn = nbase + ls[m];
                out[nn * 3 + 0] = e0 - lse;
                out[nn * 3 + 1] = e1 - lse;
                out[nn * 3 + 2] = e2 - lse;
            }
        }
    }
}

// ---------------------------------------------------------------------------

extern "C" void kernel_launch(void* const* d_in, const int* in_sizes, int n_in,
                              void* d_out, int out_size, void* d_ws, size_t ws_size,
                              hipStream_t stream) {
    const float* x       = (const float*)d_in[0];
    const int*   ei      = (const int*)d_in[1];
    const float* w1      = (const float*)d_in[2];
    const float* b1      = (const float*)d_in[3];
    const float* w2      = (const float*)d_in[4];
    const float* b2      = (const float*)d_in[5];
    const float* w3      = (const float*)d_in[6];
    const float* b3      = (const float*)d_in[7];
    const float* wg      = (const float*)d_in[8];
    const float* bg      = (const float*)d_in[9];
    const float* att_s   = (const float*)d_in[10];
    const float* att_d   = (const float*)d_in[11];
    const float* wc1     = (const float*)d_in[12];
    const float* bc1     = (const float*)d_in[13];
    const float* wc2     = (const float*)d_in[14];
    const float* bc2     = (const float*)d_in[15];
    float* out = (float*)d_out;

    const int N = in_sizes[0] / 8;
    const int E = in_sizes[1] / 2;
    const int* srcv = ei;
    const int* dstv = ei + E;

    char* ws = (char*)d_ws;
    size_t off = 0;
    auto alloc = [&](size_t bytes) -> char* {
        char* p = ws + off;
        off += (bytes + 255) & ~(size_t)255;
        return p;
    };
    int*   counts    = (int*)alloc((size_t)N * 4);
    int*   row_ptr   = (int*)alloc((size_t)(N + 1) * 4);
    int*   cursor    = (int*)alloc((size_t)N * 4);
    int*   col_src   = (int*)alloc((size_t)E * 4);
    int*   blockSums = (int*)alloc(4096 * 4);
    int*   blockOffs = (int*)alloc(4096 * 4);
    float* dinv      = (float*)alloc((size_t)N * 4);
    float* rdinv     = (float*)alloc((size_t)N * 4);
    float* xs        = (float*)alloc((size_t)N * 8 * 4);
    float* a_src     = (float*)alloc((size_t)N * 16);
    float* a_dst     = (float*)alloc((size_t)N * 16);
    float* wse       = (float*)alloc(256 * 4);
    float* wde       = (float*)alloc(256 * 4);
    float* Ccomb     = (float*)alloc(256 * 64 * 4);
    float* bcomb     = (float*)alloc(64 * 4);
    float* bufA      = (float*)alloc((size_t)N * 64 * 4);   // hs1, later h3
    float* bufB      = (float*)alloc((size_t)N * 64 * 4);   // hs2
    const int S = (N + 3) / 4;                              // stripe size
    float* aggbuf    = (float*)alloc((size_t)S * 256 * 4);  // one stripe of agg
    float* hs1 = bufA;
    float* hs2 = bufB;
    float* h3  = bufA;   // hs1 dead once layer3 runs (layer3 reads hs2 only)
    (void)ws_size; (void)n_in; (void)out_size;

    hipMemsetAsync(counts, 0, (size_t)N * 4, stream);

    const int TPB = 256;
    int gridE = (E + TPB - 1) / TPB;
    count_kernel<<<gridE, TPB, 0, stream>>>(dstv, E, counts);

    int NB = (N + 2047) / 2048;
    scan_pass1<<<NB, TPB, 0, stream>>>(counts, N, blockSums);
    scan_pass2<<<1, 64, 0, stream>>>(blockSums, NB, blockOffs);
    scan_pass3<<<NB, TPB, 0, stream>>>(counts, N, blockOffs, x,
                                       row_ptr, cursor, dinv, rdinv, xs);
    scatter_kernel<<<gridE, TPB, 0, stream>>>(srcv, dstv, E, cursor, col_src);

    att_eff_kernel<<<1, TPB, 0, stream>>>(wg, att_s, att_d, wse, wde);
    ccomb_kernel<<<257, 64, 0, stream>>>(wg, bg, wc1, bc1, Ccomb, bcomb);

    int gridN = (N + 3) / 4;
    gcn_layer1<<<gridN, TPB, 0, stream>>>(xs, w1, b1, row_ptr, col_src, dinv, N, hs1);
    gcn_layer64<false><<<gridN, TPB, 0, stream>>>(hs1, w2, b2, row_ptr, col_src,
                                                  dinv, rdinv, wse, wde, N, hs2,
                                                  nullptr, nullptr);
    gcn_layer64<true><<<gridN, TPB, 0, stream>>>(hs2, w3, b3, row_ptr, col_src,
                                                 dinv, rdinv, wse, wde, N, h3,
                                                 (float4*)a_src, (float4*)a_dst);

    // GAT + MLP in 4 stripes reusing the 25.6MB agg slab
    for (int s = 0; s < 4; ++s) {
        int nbase = s * S;
        if (nbase >= N) break;
        int ncount = min(S, N - nbase);
        int gridA = (ncount + 3) / 4;   // 1 node per wave
        gat_agg<<<gridA, TPB, 0, stream>>>(h3, (const float4*)a_src, (const float4*)a_dst,
                                           row_ptr, col_src, nbase, ncount, aggbuf);
        mlp_kernel<<<512, TPB, 0, stream>>>(aggbuf, Ccomb, bcomb, wc2, bc2,
                                            nbase, ncount, out);
    }
}